// Round 14
// baseline (181.199 us; speedup 1.0000x reference)
//
#include <hip/hip_runtime.h>
#include <math.h>

// LineFinderLoss: B=384 independent LSAs (L x 256, L<=64) + loss.
// One wave per batch; each lane owns 4 pred columns (j = lane + 64k).
// Round 14: R12 (greedy-walk int JV, fused finalization) + VALID column
// compensation to kill the degenerate L^2/2 walk:
//   m_j = min_i Q_ij;  theta = (L-8)-th smallest m_j (wave binary search);
//   v_j = min(0, m_j - theta).
// Only ~L-8 "surely matched" columns get v<0 (R3's invalid version set all
// 256). Reduced costs on compensated columns are purely geometric, so the
// greedy claim spreads rows out and the best FREE column prices at ~theta,
// ending walks after a few pops. Suboptimality only from compensated-yet-
// unmatched columns (each <= theta - m_j, small). Everything else == R12.

#define B_ 384
#define N_ 256
#define M_ 64

typedef unsigned long long u64;
typedef unsigned int u32;

#define WOFF   (1 << 20)       // key offset (reduced cost can be negative)
#define DCLAMP 0x007FFFFE      // d clamp: (DCLAMP<<8)|255 < 2^31
#define BIGF   3.0e8f          // SC bias folded into base[]
#define THF    1.0e8f          // SC detection threshold on base[]

static __device__ __forceinline__ float readlane_f32(float x, int l) {
  return __int_as_float(__builtin_amdgcn_readlane(__float_as_int(x), l));
}

// Quantized cost (same instruction sequence at every call site).
static __device__ __forceinline__ int qcost(float px_, float py_, float pz_,
                                            float base_,
                                            float lx, float ly, float lz) {
  const float t1 = __fmul_rn(px_, lx);
  const float t2 = __fmaf_rn(py_, ly, t1);
  const float t3 = __fmaf_rn(pz_, lz, t2);
  return (int)__fmaf_rn(t3, -3276.8f, base_);   // -2 * 0.05 * 2^15
}

// Two interleaved wave-min chains into lane 63 (R12).
static __device__ __forceinline__ void wave_min2_u32(u32& a, u32& b) {
  asm("s_nop 1\n\t"
      "v_min_u32_dpp %0, %0, %0 row_shr:1 row_mask:0xf bank_mask:0xf\n\t"
      "v_min_u32_dpp %1, %1, %1 row_shr:1 row_mask:0xf bank_mask:0xf\n\t"
      "v_min_u32_dpp %0, %0, %0 row_shr:2 row_mask:0xf bank_mask:0xf\n\t"
      "v_min_u32_dpp %1, %1, %1 row_shr:2 row_mask:0xf bank_mask:0xf\n\t"
      "v_min_u32_dpp %0, %0, %0 row_shr:4 row_mask:0xf bank_mask:0xf\n\t"
      "v_min_u32_dpp %1, %1, %1 row_shr:4 row_mask:0xf bank_mask:0xf\n\t"
      "v_min_u32_dpp %0, %0, %0 row_shr:8 row_mask:0xf bank_mask:0xf\n\t"
      "v_min_u32_dpp %1, %1, %1 row_shr:8 row_mask:0xf bank_mask:0xf\n\t"
      "v_min_u32_dpp %0, %0, %0 row_bcast:15 row_mask:0xa bank_mask:0xf\n\t"
      "v_min_u32_dpp %1, %1, %1 row_bcast:15 row_mask:0xa bank_mask:0xf\n\t"
      "v_min_u32_dpp %0, %0, %0 row_bcast:31 row_mask:0xc bank_mask:0xf\n\t"
      "v_min_u32_dpp %1, %1, %1 row_bcast:31 row_mask:0xc bank_mask:0xf"
      : "+v"(a), "+v"(b));
}

__global__ __launch_bounds__(64) void lsa_loss_kernel(
    const float* __restrict__ pred,
    const float* __restrict__ label,
    const int* __restrict__ label_len,
    double* __restrict__ ws,
    float* __restrict__ out)
{
  const int b = blockIdx.x;
  const int lane = threadIdx.x;  // 0..63

  __shared__ float lab_x[M_], lab_y[M_], lab_z[M_];
  __shared__ int r4c_lds[N_];    // epilogue-only inverse map

  const float* lp = label + (size_t)(b * M_ + lane) * 3;
  const float labx = lp[0], laby = lp[1], labz = lp[2];
  lab_x[lane] = labx; lab_y[lane] = laby; lab_z[lane] = labz;

  float px[4], py[4], pz[4], lc[4], lca[4], base[4], baseO[4], baseB[4];
  int v[4];
  u32 jc[4];
  const float4* pred4 = reinterpret_cast<const float4*>(pred);
#pragma unroll
  for (int k = 0; k < 4; ++k) {
    const float4 p = pred4[b * N_ + lane + 64 * k];
    px[k] = p.x; py[k] = p.y; pz[k] = p.z;
    lc[k]  = logf(__fadd_rn(p.w, 1e-5f));
    lca[k] = logf(__fadd_rn(__fsub_rn(1.0f, p.w), 1e-5f));
    const float qgf = __fmul_rn(__fsub_rn(lca[k], lc[k]), 32768.0f);
    const float npp = __fmaf_rn(p.z, p.z, __fmaf_rn(p.y, p.y, __fmul_rn(p.x, p.x)));
    base[k]  = __fmaf_rn(npp, 1638.4f, qgf);
    baseO[k] = base[k];
    baseB[k] = base[k] + BIGF;
    v[k] = 0;
    jc[k] = (u32)(lane + 64 * k);
  }
  int c4r = -1;   // col4row[lane]
  int u_reg = 0;  // u[lane]

  int L = label_len[b];
  L = (L < 1) ? 1 : ((L > M_) ? M_ : L);

  __syncthreads();  // labels visible

  // ---- Column minima m_j = min_{i<L} Q_ij (one-time, ~4k cy) ----
  int mcol[4] = {0x7FFFFFFF, 0x7FFFFFFF, 0x7FFFFFFF, 0x7FFFFFFF};
  for (int r = 0; r < L; ++r) {
    const float lx = readlane_f32(labx, r);
    const float ly = readlane_f32(laby, r);
    const float lz = readlane_f32(labz, r);
#pragma unroll
    for (int k = 0; k < 4; ++k) {
      const int q = qcost(px[k], py[k], pz[k], base[k], lx, ly, lz);
      mcol[k] = (q < mcol[k]) ? q : mcol[k];
    }
  }
  // ---- theta = largest t with #{m_j < t} <= R, R = max(L-8, 1) ----
  {
    const int R = (L > 9) ? (L - 8) : 1;
    int lo = -(1 << 20), hi = (1 << 20);   // cnt(lo)=0<=R, cnt(hi)=256>R
    while (hi - lo > 1) {
      const int mid = lo + ((hi - lo) >> 1);
      const int cnt = __popcll(__ballot(mcol[0] < mid))
                    + __popcll(__ballot(mcol[1] < mid))
                    + __popcll(__ballot(mcol[2] < mid))
                    + __popcll(__ballot(mcol[3] < mid));
      if (cnt <= R) lo = mid; else hi = mid;
    }
    const int theta = lo;
#pragma unroll
    for (int k = 0; k < 4; ++k) {
      const int vc = mcol[k] - theta;
      v[k] = (vc < 0) ? vc : 0;   // v<0 only on "surely matched" columns
    }
  }

  // ---- Warm start: u_i = min_j (Q_ij - v_j), greedy claim of argmins ----
  for (int r = 0; r < L; ++r) {
    const float lx = readlane_f32(labx, r);
    const float ly = readlane_f32(laby, r);
    const float lz = readlane_f32(labz, r);
    u32 cand[4];
#pragma unroll
    for (int k = 0; k < 4; ++k) {
      const int q = (qcost(px[k], py[k], pz[k], base[k], lx, ly, lz) - v[k]) + WOFF;
      cand[k] = ((u32)q << 8) | jc[k];
    }
    u32 ca = (cand[0] < cand[1]) ? cand[0] : cand[1];
    u32 cb = (cand[2] < cand[3]) ? cand[2] : cand[3];
    wave_min2_u32(ca, cb);
    const u32 wa = (u32)__builtin_amdgcn_readlane((int)ca, 63);
    const u32 wb = (u32)__builtin_amdgcn_readlane((int)cb, 63);
    const u32 wk = (wa < wb) ? wa : wb;
    const int j1 = (int)(wk & 0xFF);
    if (lane == r) u_reg = (int)(wk >> 8) - WOFF;
    const bool taken = __ballot(c4r == j1) != 0ull;
    if (!taken && lane == r) c4r = j1;
  }
  u64 free_mask = __ballot((lane < L) && (c4r < 0));

  // ---- Greedy-walk SSP for the remaining free rows (R12, unchanged) ----
  while (free_mask) {
    const int cur_row = (int)__builtin_ctzll(free_mask);
    free_mask &= free_mask - 1;

    u32 shk[4] = {0x7FFFFFFFu, 0x7FFFFFFFu, 0x7FFFFFFFu, 0x7FFFFFFFu};
    int mvj = 0, joined = 0, min_val = 0;
    int i_cur = cur_row;
    int u_i = __builtin_amdgcn_readlane(u_reg, i_cur);
    float lx = readlane_f32(labx, i_cur);
    float ly = readlane_f32(laby, i_cur);
    float lz = readlane_f32(labz, i_cur);
    int t = 0 - u_i;
    int sink = -1;

    while (true) {
      u32 cand[4];
#pragma unroll
      for (int k = 0; k < 4; ++k) {
        const int tv = t - v[k];
        int dd = qcost(px[k], py[k], pz[k], base[k], lx, ly, lz) + tv;
        dd = (dd < DCLAMP) ? dd : DCLAMP;
        const u32 rkey = ((u32)dd << 8) | jc[k];
        const u32 skey = ((u32)dd << 8) | (u32)i_cur;
        shk[k] = (skey < shk[k]) ? skey : shk[k];
        cand[k] = rkey;
      }
      u32 ca = (cand[0] < cand[1]) ? cand[0] : cand[1];
      u32 cb = (cand[2] < cand[3]) ? cand[2] : cand[3];
      wave_min2_u32(ca, cb);
      const u32 wa = (u32)__builtin_amdgcn_readlane((int)ca, 63);
      const u32 wb = (u32)__builtin_amdgcn_readlane((int)cb, 63);
      const u32 wk = (wa < wb) ? wa : wb;
      const int j_min = (int)(wk & 0xFF);
      min_val = (int)(wk >> 8);
      const int kk = j_min >> 6;
      const bool selfc = (lane == (j_min & 63));
      base[0] = (selfc && kk == 0) ? baseB[0] : base[0];
      base[1] = (selfc && kk == 1) ? baseB[1] : base[1];
      base[2] = (selfc && kk == 2) ? baseB[2] : base[2];
      base[3] = (selfc && kk == 3) ? baseB[3] : base[3];
      const bool own = (c4r == j_min);
      const u64 om = __ballot(own);
      if (om == 0ull) { sink = j_min; break; }
      i_cur = (int)__builtin_ctzll(om);
      if (own) { mvj = min_val; joined = 1; }
      u_i = __builtin_amdgcn_readlane(u_reg, i_cur);
      lx = readlane_f32(labx, i_cur);
      ly = readlane_f32(laby, i_cur);
      lz = readlane_f32(labz, i_cur);
      t = min_val - u_i;
    }

    if (lane == cur_row)  u_reg += min_val;
    else if (joined)      u_reg += min_val - mvj;
#pragma unroll
    for (int k = 0; k < 4; ++k) {
      if (base[k] > THF) {
        v[k] -= (min_val - (int)(shk[k] >> 8));
        base[k] = baseO[k];
      }
    }

    {
      int j = sink;
      while (true) {
        const int kkj = j >> 6, lj = j & 63;
        const int s0 = __builtin_amdgcn_readlane((int)shk[0], lj);
        const int s1 = __builtin_amdgcn_readlane((int)shk[1], lj);
        const int s2 = __builtin_amdgcn_readlane((int)shk[2], lj);
        const int s3 = __builtin_amdgcn_readlane((int)shk[3], lj);
        const int ps = (kkj == 0) ? s0 : (kkj == 1) ? s1 : (kkj == 2) ? s2 : s3;
        const int ii = ps & 0xFF;
        const int jn = __builtin_amdgcn_readlane(c4r, ii);
        if (lane == ii) c4r = j;
        if (ii == cur_row) break;
        j = jn;
      }
    }
  }

  // ---- Epilogue: rebuild row4col once via LDS inverse of c4r ----
#pragma unroll
  for (int k = 0; k < 4; ++k) r4c_lds[lane + 64 * k] = -1;
  __syncthreads();
  if (c4r >= 0) r4c_lds[c4r] = lane;
  __syncthreads();

  double loc = 0.0, cpos = 0.0, cneg = 0.0;
#pragma unroll
  for (int k = 0; k < 4; ++k) {
    const int l = r4c_lds[lane + 64 * k];
    if (l >= 0) {
      const float d0 = __fsub_rn(px[k], lab_x[l]);
      const float d1 = __fsub_rn(py[k], lab_y[l]);
      const float d2 = __fsub_rn(pz[k], lab_z[l]);
      const float nd = __fadd_rn(__fadd_rn(__fmul_rn(d0, d0), __fmul_rn(d1, d1)),
                                 __fmul_rn(d2, d2));
      loc += (double)nd;
      cpos -= (double)lc[k];
    } else {
      cneg -= (double)lca[k];
    }
  }
  for (int off = 32; off >= 1; off >>= 1) {
    loc += __shfl_xor(loc, off, 64);
    cpos += __shfl_xor(cpos, off, 64);
    cneg += __shfl_xor(cneg, off, 64);
  }

  // ---- Fused finalization via device-scope atomics + ticket counter ----
  if (lane == 0) {
    atomicAdd(&ws[0], loc);
    atomicAdd(&ws[1], cpos + cneg + 1e-4);
    if (b == B_ - 1) { atomicAdd(&ws[2], cpos); atomicAdd(&ws[3], cneg); }
    __threadfence();
    unsigned int* cnt = (unsigned int*)(ws + 4);
    const unsigned int old = atomicAdd(cnt, 1u);
    if (old == (unsigned int)(B_ - 1)) {
      __threadfence();
      const double loc_t  = atomicAdd(&ws[0], 0.0);
      const double conf_t = atomicAdd(&ws[1], 0.0);
      const double cpos_l = atomicAdd(&ws[2], 0.0);
      const double cneg_l = atomicAdd(&ws[3], 0.0);
      const double lloc = 0.1 * (loc_t * 0.5);  // ALPHA * location_loss
      out[0] = (float)(lloc + conf_t);
      out[1] = (float)lloc;
      out[2] = (float)cpos_l;
      out[3] = (float)cneg_l;
    }
  }
}

extern "C" void kernel_launch(void* const* d_in, const int* in_sizes, int n_in,
                              void* d_out, int out_size, void* d_ws, size_t ws_size,
                              hipStream_t stream) {
  const float* pred = (const float*)d_in[0];       // (B, N, 4) fp32
  const float* label = (const float*)d_in[1];      // (B, M, 3) fp32
  const int* label_len = (const int*)d_in[2];      // (B,) int32
  double* ws = (double*)d_ws;
  float* out = (float*)d_out;

  hipMemsetAsync(d_ws, 0, 64, stream);  // 4 f64 accumulators + ticket
  lsa_loss_kernel<<<B_, 64, 0, stream>>>(pred, label, label_len, ws, out);
}

// Round 15
// 152.863 us; speedup vs baseline: 1.1854x; 1.1854x over previous
//
#include <hip/hip_runtime.h>
#include <math.h>

// LineFinderLoss: B=384 independent LSAs (L x 256, L<=64) + loss.
// One wave per batch; each lane owns 4 pred columns (j = lane + 64k).
// Round 15 = R12 verbatim (session best: kernel 98.7us, total 153.6us).
// R13 (eps-ARR) and R14 (column compensation) both REGRESSED pops —
// together with R7 (eps=0 ARR) this establishes that ~L^2/2 pops is an
// equilibrium of the greedy-walk dynamics on this column-dominated cost;
// dual perturbations make walks longer. R11 (exact Dijkstra) floods 10x.
// Structure: greedy-walk integer JV, issue-bound pop loop (~115 cy/pop):
//  - dual interleaved v_min_u32_dpp chains, no s_nops
//  - owner lookup via ballot(c4r == j_min)
//  - prev-row folded into shk low byte
//  - SC retire via pre-biased base[] cndmask
//  - fused finalization via device-scope f64 atomics + ticket counter.

#define B_ 384
#define N_ 256
#define M_ 64

typedef unsigned long long u64;
typedef unsigned int u32;

#define WOFF   (1 << 20)       // warm-start key offset (Q can be negative)
#define DCLAMP 0x007FFFFE      // d clamp: (DCLAMP<<8)|255 < 2^31
#define BIGF   3.0e8f          // SC bias folded into base[]
#define THF    1.0e8f          // SC detection threshold on base[]

static __device__ __forceinline__ float readlane_f32(float x, int l) {
  return __int_as_float(__builtin_amdgcn_readlane(__float_as_int(x), l));
}

// Quantized cost (same instruction sequence at every call site).
static __device__ __forceinline__ int qcost(float px_, float py_, float pz_,
                                            float base_,
                                            float lx, float ly, float lz) {
  const float t1 = __fmul_rn(px_, lx);
  const float t2 = __fmaf_rn(py_, ly, t1);
  const float t3 = __fmaf_rn(pz_, lz, t2);
  return (int)__fmaf_rn(t3, -3276.8f, base_);   // -2 * 0.05 * 2^15
}

// Two interleaved wave-min chains into lane 63. Each chain's step is spaced
// by the other chain's instruction (2 cy) — covers the VALU->DPP hazard.
static __device__ __forceinline__ void wave_min2_u32(u32& a, u32& b) {
  asm("s_nop 1\n\t"
      "v_min_u32_dpp %0, %0, %0 row_shr:1 row_mask:0xf bank_mask:0xf\n\t"
      "v_min_u32_dpp %1, %1, %1 row_shr:1 row_mask:0xf bank_mask:0xf\n\t"
      "v_min_u32_dpp %0, %0, %0 row_shr:2 row_mask:0xf bank_mask:0xf\n\t"
      "v_min_u32_dpp %1, %1, %1 row_shr:2 row_mask:0xf bank_mask:0xf\n\t"
      "v_min_u32_dpp %0, %0, %0 row_shr:4 row_mask:0xf bank_mask:0xf\n\t"
      "v_min_u32_dpp %1, %1, %1 row_shr:4 row_mask:0xf bank_mask:0xf\n\t"
      "v_min_u32_dpp %0, %0, %0 row_shr:8 row_mask:0xf bank_mask:0xf\n\t"
      "v_min_u32_dpp %1, %1, %1 row_shr:8 row_mask:0xf bank_mask:0xf\n\t"
      "v_min_u32_dpp %0, %0, %0 row_bcast:15 row_mask:0xa bank_mask:0xf\n\t"
      "v_min_u32_dpp %1, %1, %1 row_bcast:15 row_mask:0xa bank_mask:0xf\n\t"
      "v_min_u32_dpp %0, %0, %0 row_bcast:31 row_mask:0xc bank_mask:0xf\n\t"
      "v_min_u32_dpp %1, %1, %1 row_bcast:31 row_mask:0xc bank_mask:0xf"
      : "+v"(a), "+v"(b));
}

__global__ __launch_bounds__(64) void lsa_loss_kernel(
    const float* __restrict__ pred,
    const float* __restrict__ label,
    const int* __restrict__ label_len,
    double* __restrict__ ws,
    float* __restrict__ out)
{
  const int b = blockIdx.x;
  const int lane = threadIdx.x;  // 0..63

  __shared__ float lab_x[M_], lab_y[M_], lab_z[M_];
  __shared__ int r4c_lds[N_];    // epilogue-only inverse map

  const float* lp = label + (size_t)(b * M_ + lane) * 3;
  const float labx = lp[0], laby = lp[1], labz = lp[2];
  lab_x[lane] = labx; lab_y[lane] = laby; lab_z[lane] = labz;

  float px[4], py[4], pz[4], lc[4], lca[4], base[4], baseO[4], baseB[4];
  int v[4];
  u32 jc[4];
  const float4* pred4 = reinterpret_cast<const float4*>(pred);
#pragma unroll
  for (int k = 0; k < 4; ++k) {
    const float4 p = pred4[b * N_ + lane + 64 * k];
    px[k] = p.x; py[k] = p.y; pz[k] = p.z;
    lc[k]  = logf(__fadd_rn(p.w, 1e-5f));
    lca[k] = logf(__fadd_rn(__fsub_rn(1.0f, p.w), 1e-5f));
    const float qgf = __fmul_rn(__fsub_rn(lca[k], lc[k]), 32768.0f);
    const float npp = __fmaf_rn(p.z, p.z, __fmaf_rn(p.y, p.y, __fmul_rn(p.x, p.x)));
    base[k]  = __fmaf_rn(npp, 1638.4f, qgf);
    baseO[k] = base[k];
    baseB[k] = base[k] + BIGF;
    v[k] = 0;
    jc[k] = (u32)(lane + 64 * k);
  }
  int c4r = -1;   // col4row[lane]
  int u_reg = 0;  // u[lane]

  int L = label_len[b];
  L = (L < 1) ? 1 : ((L > M_) ? M_ : L);

  __syncthreads();  // labels visible (epilogue gather)

  // ---- Warm start: u_i = min_j Q_ij, greedy claim of argmin columns ----
  for (int r = 0; r < L; ++r) {
    const float lx = readlane_f32(labx, r);
    const float ly = readlane_f32(laby, r);
    const float lz = readlane_f32(labz, r);
    u32 cand[4];
#pragma unroll
    for (int k = 0; k < 4; ++k) {
      const int q = qcost(px[k], py[k], pz[k], base[k], lx, ly, lz);
      cand[k] = ((u32)(q + WOFF) << 8) | jc[k];
    }
    u32 ca = (cand[0] < cand[1]) ? cand[0] : cand[1];
    u32 cb = (cand[2] < cand[3]) ? cand[2] : cand[3];
    wave_min2_u32(ca, cb);
    const u32 wa = (u32)__builtin_amdgcn_readlane((int)ca, 63);
    const u32 wb = (u32)__builtin_amdgcn_readlane((int)cb, 63);
    const u32 wk = (wa < wb) ? wa : wb;
    const int j1 = (int)(wk & 0xFF);
    if (lane == r) u_reg = (int)(wk >> 8) - WOFF;
    const bool taken = __ballot(c4r == j1) != 0ull;
    if (!taken && lane == r) c4r = j1;
  }
  u64 free_mask = __ballot((lane < L) && (c4r < 0));

  // ---- Greedy-walk SSP for free rows ----
  while (free_mask) {
    const int cur_row = (int)__builtin_ctzll(free_mask);
    free_mask &= free_mask - 1;

    u32 shk[4] = {0x7FFFFFFFu, 0x7FFFFFFFu, 0x7FFFFFFFu, 0x7FFFFFFFu};
    int mvj = 0, joined = 0, min_val = 0;
    int i_cur = cur_row;
    int u_i = __builtin_amdgcn_readlane(u_reg, i_cur);
    float lx = readlane_f32(labx, i_cur);
    float ly = readlane_f32(laby, i_cur);
    float lz = readlane_f32(labz, i_cur);
    int t = 0 - u_i;
    int sink = -1;

    while (true) {
      u32 cand[4];
#pragma unroll
      for (int k = 0; k < 4; ++k) {
        const int tv = t - v[k];
        int dd = qcost(px[k], py[k], pz[k], base[k], lx, ly, lz) + tv;
        dd = (dd < DCLAMP) ? dd : DCLAMP;          // also caps SC-biased dd
        const u32 rkey = ((u32)dd << 8) | jc[k];   // reduce key (j payload)
        const u32 skey = ((u32)dd << 8) | (u32)i_cur;  // prev-in-key
        shk[k] = (skey < shk[k]) ? skey : shk[k];
        cand[k] = rkey;
      }
      u32 ca = (cand[0] < cand[1]) ? cand[0] : cand[1];
      u32 cb = (cand[2] < cand[3]) ? cand[2] : cand[3];
      wave_min2_u32(ca, cb);
      const u32 wa = (u32)__builtin_amdgcn_readlane((int)ca, 63);
      const u32 wb = (u32)__builtin_amdgcn_readlane((int)cb, 63);
      const u32 wk = (wa < wb) ? wa : wb;
      const int j_min = (int)(wk & 0xFF);
      min_val = (int)(wk >> 8);
      const int kk = j_min >> 6;
      const bool selfc = (lane == (j_min & 63));
      // Retire popped column: base <- pre-biased copy (1 cndmask per k).
      base[0] = (selfc && kk == 0) ? baseB[0] : base[0];
      base[1] = (selfc && kk == 1) ? baseB[1] : base[1];
      base[2] = (selfc && kk == 2) ? baseB[2] : base[2];
      base[3] = (selfc && kk == 3) ? baseB[3] : base[3];
      // Owner row via the inverse map held in c4r.
      const bool own = (c4r == j_min);
      const u64 om = __ballot(own);
      if (om == 0ull) { sink = j_min; break; }
      i_cur = (int)__builtin_ctzll(om);
      if (own) { mvj = min_val; joined = 1; }
      u_i = __builtin_amdgcn_readlane(u_reg, i_cur);
      lx = readlane_f32(labx, i_cur);
      ly = readlane_f32(laby, i_cur);
      lz = readlane_f32(labz, i_cur);
      t = min_val - u_i;
    }

    // Dual updates (SC detected via biased base).
    if (lane == cur_row)  u_reg += min_val;
    else if (joined)      u_reg += min_val - mvj;
#pragma unroll
    for (int k = 0; k < 4; ++k) {
      if (base[k] > THF) {
        v[k] -= (min_val - (int)(shk[k] >> 8));
        base[k] = baseO[k];
      }
    }

    // Augment: lockstep walk; prev row = low byte of shk.
    {
      int j = sink;
      while (true) {
        const int kkj = j >> 6, lj = j & 63;
        const int s0 = __builtin_amdgcn_readlane((int)shk[0], lj);
        const int s1 = __builtin_amdgcn_readlane((int)shk[1], lj);
        const int s2 = __builtin_amdgcn_readlane((int)shk[2], lj);
        const int s3 = __builtin_amdgcn_readlane((int)shk[3], lj);
        const int ps = (kkj == 0) ? s0 : (kkj == 1) ? s1 : (kkj == 2) ? s2 : s3;
        const int ii = ps & 0xFF;
        const int jn = __builtin_amdgcn_readlane(c4r, ii);
        if (lane == ii) c4r = j;
        if (ii == cur_row) break;
        j = jn;
      }
    }
  }

  // ---- Epilogue: rebuild row4col once via LDS inverse of c4r ----
#pragma unroll
  for (int k = 0; k < 4; ++k) r4c_lds[lane + 64 * k] = -1;
  __syncthreads();
  if (c4r >= 0) r4c_lds[c4r] = lane;
  __syncthreads();

  double loc = 0.0, cpos = 0.0, cneg = 0.0;
#pragma unroll
  for (int k = 0; k < 4; ++k) {
    const int l = r4c_lds[lane + 64 * k];
    if (l >= 0) {
      const float d0 = __fsub_rn(px[k], lab_x[l]);
      const float d1 = __fsub_rn(py[k], lab_y[l]);
      const float d2 = __fsub_rn(pz[k], lab_z[l]);
      const float nd = __fadd_rn(__fadd_rn(__fmul_rn(d0, d0), __fmul_rn(d1, d1)),
                                 __fmul_rn(d2, d2));
      loc += (double)nd;
      cpos -= (double)lc[k];
    } else {
      cneg -= (double)lca[k];
    }
  }
  for (int off = 32; off >= 1; off >>= 1) {
    loc += __shfl_xor(loc, off, 64);
    cpos += __shfl_xor(cpos, off, 64);
    cneg += __shfl_xor(cneg, off, 64);
  }

  // ---- Fused finalization via device-scope atomics + ticket counter ----
  if (lane == 0) {
    atomicAdd(&ws[0], loc);
    atomicAdd(&ws[1], cpos + cneg + 1e-4);
    if (b == B_ - 1) { atomicAdd(&ws[2], cpos); atomicAdd(&ws[3], cneg); }
    __threadfence();
    unsigned int* cnt = (unsigned int*)(ws + 4);
    const unsigned int old = atomicAdd(cnt, 1u);
    if (old == (unsigned int)(B_ - 1)) {
      __threadfence();
      const double loc_t  = atomicAdd(&ws[0], 0.0);
      const double conf_t = atomicAdd(&ws[1], 0.0);
      const double cpos_l = atomicAdd(&ws[2], 0.0);
      const double cneg_l = atomicAdd(&ws[3], 0.0);
      const double lloc = 0.1 * (loc_t * 0.5);  // ALPHA * location_loss
      out[0] = (float)(lloc + conf_t);
      out[1] = (float)lloc;
      out[2] = (float)cpos_l;
      out[3] = (float)cneg_l;
    }
  }
}

extern "C" void kernel_launch(void* const* d_in, const int* in_sizes, int n_in,
                              void* d_out, int out_size, void* d_ws, size_t ws_size,
                              hipStream_t stream) {
  const float* pred = (const float*)d_in[0];       // (B, N, 4) fp32
  const float* label = (const float*)d_in[1];      // (B, M, 3) fp32
  const int* label_len = (const int*)d_in[2];      // (B,) int32
  double* ws = (double*)d_ws;
  float* out = (float*)d_out;

  hipMemsetAsync(d_ws, 0, 64, stream);  // 4 f64 accumulators + ticket
  lsa_loss_kernel<<<B_, 64, 0, stream>>>(pred, label, label_len, ws, out);
}